// Round 3
// baseline (520.129 us; speedup 1.0000x reference)
//
#include <hip/hip_runtime.h>
#include <hip/hip_bf16.h>
#include <stdint.h>

static constexpr int Bsz = 1024;
static constexpr int TT  = 256;
static constexpr int FF  = 124;
static constexpr int HH  = 64;
static constexpr int GG  = 256;   // 4*H
static constexpr int BB  = 16;    // batch rows per block
static constexpr int C_OFF = Bsz * 8;
static constexpr int H_OFF = C_OFF + Bsz * HH;

// packed-weight workspace layout (uint16_t units)
static constexpr int WXH_U16 = 24 * 256 * 8;      // 49152   (Wx/Wh frags)
static constexpr int W1P_U16 = 256 * 4096;        // 1048576 (W1 frags, 256 blocks x 8KB)
static constexpr size_t WS_NEED = (size_t)(WXH_U16 + W1P_U16) * 2;  // ~2.1 MB

typedef __attribute__((ext_vector_type(8))) short bf16x8;
typedef __attribute__((ext_vector_type(4))) float f32x4;

#define MFMA16 __builtin_amdgcn_mfma_f32_16x16x32_bf16

__device__ __forceinline__ uint16_t f2bf(float x) {
  union { float f; uint32_t u; } v; v.f = x;
  return (uint16_t)((v.u + 0x7FFFu + ((v.u >> 16) & 1u)) >> 16);
}
__device__ __forceinline__ float fsig(float x) {
  return __builtin_amdgcn_rcpf(1.0f + __builtin_amdgcn_exp2f(-1.4426950408889634f * x));
}
__device__ __forceinline__ float ftanh(float x) {
  float e = __builtin_amdgcn_exp2f(-2.8853900817779268f * x);
  return (1.0f - e) * __builtin_amdgcn_rcpf(1.0f + e);
}
__device__ __forceinline__ void dma16(const void* g, void* l) {
  __builtin_amdgcn_global_load_lds(
      (const __attribute__((address_space(1))) uint32_t*)g,
      (__attribute__((address_space(3))) uint32_t*)l, 16, 0, 0);
}

// ---------------- pre-pass: pack Wx/Wh/W1 into bf16 fragment order ----------------
__global__ __launch_bounds__(256) void pack_weights(
    const float* __restrict__ Wx, const float* __restrict__ Wh,
    const float* __restrict__ W1, uint16_t* __restrict__ wsp)
{
  const int c = blockIdx.x * 256 + threadIdx.x;
  uint16_t v[8];
  size_t dst;
  if (c < 6144) {                       // Wx/Wh frags: [f 0..23][tid 0..255][8]
    const int f = c >> 8, tid = c & 255;
    const int w = tid >> 6, l = tid & 63;
    const int kgl = (l >> 4) * 8, r16 = l & 15;
    if (f < 16) {
      const int g = f >> 2, kf = f & 3;
      const int col = g * 64 + w * 16 + r16;
#pragma unroll
      for (int j = 0; j < 8; ++j) v[j] = f2bf(Wx[(size_t)(kf * 32 + kgl + j) * GG + col]);
    } else {
      const int g = (f - 16) >> 1, kf = (f - 16) & 1;
      const int col = g * 64 + w * 16 + r16;
#pragma unroll
      for (int j = 0; j < 8; ++j) v[j] = f2bf(Wh[(size_t)(kf * 32 + kgl + j) * GG + col]);
    }
    dst = (size_t)c * 8;
  } else if (c < 6144 + 131072) {       // W1 frags: [t][w][half][l][8]
    const int cc = c - 6144;
    const int t = cc >> 9, r = cc & 511;
    const int w = r >> 7, half = (r >> 6) & 1, l = r & 63;
    const int row0 = t * 64 + half * 32 + (l >> 4) * 8;
    const int col = w * 16 + (l & 15);
#pragma unroll
    for (int j = 0; j < 8; ++j) v[j] = f2bf(W1[(size_t)(row0 + j) * 64 + col]);
    dst = (size_t)WXH_U16 + (size_t)cc * 8;
  } else return;
  uint4 pk;
  pk.x = (uint32_t)v[0] | ((uint32_t)v[1] << 16);
  pk.y = (uint32_t)v[2] | ((uint32_t)v[3] << 16);
  pk.z = (uint32_t)v[4] | ((uint32_t)v[5] << 16);
  pk.w = (uint32_t)v[6] | ((uint32_t)v[7] << 16);
  *(uint4*)(wsp + dst) = pk;
}

// ---------------- main fused kernel (raw barrier + counted vmcnt) ----------------
__global__ __launch_bounds__(256, 1) void actor_lstm(
    const float* __restrict__ x,  const float* __restrict__ pa,
    const float* __restrict__ bg, const uint16_t* __restrict__ wsp,
    const float* __restrict__ b1, const float* __restrict__ W2,
    const float* __restrict__ b2, const float* __restrict__ W3,
    const float* __restrict__ b3, float* __restrict__ out)
{
  __shared__ __align__(16) uint16_t xs_lds[2][BB * 128];  // 8 KB
  __shared__ __align__(16) uint16_t h_lds[2][BB * HH];    // 4 KB
  __shared__ __align__(16) uint16_t w1_lds[3][4096];      // 24 KB (3-deep ring)
  __shared__ float w2_lds[64 * 64];                       // 16 KB
  __shared__ float mlp_a[BB * 65];
  __shared__ float mlp_b[BB * 65];

  const int tid   = threadIdx.x;
  const int w     = tid >> 6;
  const int l     = tid & 63;
  const int row16 = l & 15;
  const int kg    = l >> 4;
  const int b0    = blockIdx.x * BB;
  const int swz   = (row16 & 7) << 4;

  // persistent B-frags from packed blob: 24 coalesced b128 loads
  bf16x8 frag[24];
#pragma unroll
  for (int f = 0; f < 24; ++f)
    frag[f] = *(const bf16x8*)(wsp + ((size_t)f * 256 + tid) * 8);
  float bias4[4];
#pragma unroll
  for (int g = 0; g < 4; ++g) bias4[g] = bg[g * 64 + w * 16 + row16];

  for (int i = tid; i < 64 * 64; i += 256) w2_lds[i] = W2[i];
  reinterpret_cast<uint64_t*>(&h_lds[0][0])[tid] = 0ull;   // h_{-1} = 0

  // xs staging geometry
  const int srow = tid >> 4, li = tid & 15;
  const int st_byte = srow * 256 + ((li << 4) ^ ((srow & 7) << 4));

  // stage xs(0) into buf0
  {
    const size_t base = (size_t)(b0 + srow) * TT + 0;
    float4 fa, fb;
    if (li < 15) { fa = *(const float4*)(x + base * FF + li * 8);
                   fb = *(const float4*)(x + base * FF + li * 8 + 4); }
    else         { fa = *(const float4*)(x + base * FF + 120);
                   fb = *(const float4*)(pa + base * 4); }
    uint4 pk;
    pk.x = (uint32_t)f2bf(fa.x) | ((uint32_t)f2bf(fa.y) << 16);
    pk.y = (uint32_t)f2bf(fa.z) | ((uint32_t)f2bf(fa.w) << 16);
    pk.z = (uint32_t)f2bf(fb.x) | ((uint32_t)f2bf(fb.y) << 16);
    pk.w = (uint32_t)f2bf(fb.z) | ((uint32_t)f2bf(fb.w) << 16);
    *(uint4*)((char*)&xs_lds[0][0] + st_byte) = pk;
  }

  // W1 DMA prologue: buf0 <- block 0 (dummy, h_{-1}=0), buf1 <- block 0
  const char* w1g = (const char*)(wsp + WXH_U16);
  {
    const char* gs = w1g + w * 2048 + l * 16;
    char* ld0 = (char*)&w1_lds[0][0] + w * 2048;
    dma16(gs, ld0);        dma16(gs + 1024, ld0 + 1024);
    char* ld1 = (char*)&w1_lds[1][0] + w * 2048;
    dma16(gs, ld1);        dma16(gs + 1024, ld1 + 1024);
  }
  // prefetch xs(1) into regs
  float4 pfa, pfb;
  {
    const size_t base = (size_t)(b0 + srow) * TT + 1;
    if (li < 15) { pfa = *(const float4*)(x + base * FF + li * 8);
                   pfb = *(const float4*)(x + base * FF + li * 8 + 4); }
    else         { pfa = *(const float4*)(x + base * FF + 120);
                   pfb = *(const float4*)(pa + base * 4); }
  }

  f32x4 cacc = {0.f, 0.f, 0.f, 0.f};
  f32x4 wacc = {0.f, 0.f, 0.f, 0.f};

#pragma unroll 1
  for (int t = 0; t < TT; ++t) {
    // counted drain: 4 newest vmem ops (DMA(t+1)x2 + xs-load x2) may stay in flight;
    // everything older (incl. this iter's W1 DMA batch) is complete. h writes visible.
    asm volatile("s_waitcnt vmcnt(4) lgkmcnt(0)" ::: "memory");
    __builtin_amdgcn_s_barrier();
    asm volatile("" ::: "memory");

    const int bi = t % 3;
    const char* xb = (const char*)&xs_lds[t & 1][0];
    const char* hb = (const char*)&h_lds[t & 1][0];
    const char* wb = (const char*)&w1_lds[0][0] + bi * 8192 + w * 2048 + l * 16;

    bf16x8 ah0 = *(const bf16x8*)(hb + row16 * 128 + (((0 + kg) << 4) ^ swz));
    bf16x8 ah1 = *(const bf16x8*)(hb + row16 * 128 + (((4 + kg) << 4) ^ swz));
    bf16x8 bw1a = *(const bf16x8*)(wb);
    bf16x8 bw1b = *(const bf16x8*)(wb + 1024);
    bf16x8 ax0 = *(const bf16x8*)(xb + row16 * 256 + (((0 * 4 + kg) << 4) ^ swz));
    bf16x8 ax1 = *(const bf16x8*)(xb + row16 * 256 + (((1 * 4 + kg) << 4) ^ swz));
    bf16x8 ax2 = *(const bf16x8*)(xb + row16 * 256 + (((2 * 4 + kg) << 4) ^ swz));
    bf16x8 ax3 = *(const bf16x8*)(xb + row16 * 256 + (((3 * 4 + kg) << 4) ^ swz));

    f32x4 g0 = {bias4[0], bias4[0], bias4[0], bias4[0]};
    f32x4 g1 = {bias4[1], bias4[1], bias4[1], bias4[1]};
    f32x4 g2 = {bias4[2], bias4[2], bias4[2], bias4[2]};
    f32x4 g3 = {bias4[3], bias4[3], bias4[3], bias4[3]};
    g0 = MFMA16(ax0, frag[0*4+0], g0, 0, 0, 0);
    g1 = MFMA16(ax0, frag[1*4+0], g1, 0, 0, 0);
    g2 = MFMA16(ax0, frag[2*4+0], g2, 0, 0, 0);
    g3 = MFMA16(ax0, frag[3*4+0], g3, 0, 0, 0);
    g0 = MFMA16(ax1, frag[0*4+1], g0, 0, 0, 0);
    g1 = MFMA16(ax1, frag[1*4+1], g1, 0, 0, 0);
    g2 = MFMA16(ax1, frag[2*4+1], g2, 0, 0, 0);
    g3 = MFMA16(ax1, frag[3*4+1], g3, 0, 0, 0);
    g0 = MFMA16(ax2, frag[0*4+2], g0, 0, 0, 0);
    g1 = MFMA16(ax2, frag[1*4+2], g1, 0, 0, 0);
    g2 = MFMA16(ax2, frag[2*4+2], g2, 0, 0, 0);
    g3 = MFMA16(ax2, frag[3*4+2], g3, 0, 0, 0);
    g0 = MFMA16(ax3, frag[0*4+3], g0, 0, 0, 0);
    g1 = MFMA16(ax3, frag[1*4+3], g1, 0, 0, 0);
    g2 = MFMA16(ax3, frag[2*4+3], g2, 0, 0, 0);
    g3 = MFMA16(ax3, frag[3*4+3], g3, 0, 0, 0);
    g0 = MFMA16(ah0, frag[16+0*2+0], g0, 0, 0, 0);
    g1 = MFMA16(ah0, frag[16+1*2+0], g1, 0, 0, 0);
    g2 = MFMA16(ah0, frag[16+2*2+0], g2, 0, 0, 0);
    g3 = MFMA16(ah0, frag[16+3*2+0], g3, 0, 0, 0);
    g0 = MFMA16(ah1, frag[16+0*2+1], g0, 0, 0, 0);
    g1 = MFMA16(ah1, frag[16+1*2+1], g1, 0, 0, 0);
    g2 = MFMA16(ah1, frag[16+2*2+1], g2, 0, 0, 0);
    g3 = MFMA16(ah1, frag[16+3*2+1], g3, 0, 0, 0);
    // flat@W1 rides along: wacc += h_{t-1} * W1block(t-1)  (t=0: ah=0 -> +0)
    wacc = MFMA16(ah0, bw1a, wacc, 0, 0, 0);
    wacc = MFMA16(ah1, bw1b, wacc, 0, 0, 0);

    // lane-local LSTM update -> h_t into other buffer
    const int kcol = w * 16 + row16;
#pragma unroll
    for (int jj = 0; jj < 4; ++jj) {
      float i_ = fsig(g0[jj]);
      float f_ = fsig(g1[jj]);
      float gv = ftanh(g2[jj]);
      float o_ = fsig(g3[jj]);
      float cn = f_ * cacc[jj] + i_ * gv;
      cacc[jj] = cn;
      float hv = o_ * ftanh(cn);
      const int row = kg * 4 + jj;
      *(uint16_t*)((char*)&h_lds[(t + 1) & 1][0] + row * 128 +
                   (((kcol >> 3) << 4) ^ ((row & 7) << 4)) + (kcol & 7) * 2) = f2bf(hv);
      if (t == TT - 1) {
        out[C_OFF + (size_t)(b0 + row) * HH + kcol] = cn;
        out[H_OFF + (size_t)(b0 + row) * HH + kcol] = hv;
      }
    }

    // issue W1 DMA for iter t+2 (source block min(t+1,255); always issue to keep vmcnt uniform)
    {
      const int sb_ = (t + 1 < TT) ? (t + 1) : (TT - 1);
      const char* gs = w1g + (size_t)sb_ * 8192 + w * 2048 + l * 16;
      char* ld = (char*)&w1_lds[0][0] + ((t + 2) % 3) * 8192 + w * 2048;
      dma16(gs, ld);
      dma16(gs + 1024, ld + 1024);
    }
    // write xs(t+1) regs -> LDS buf[(t+1)&1]; then load xs(t+2) regs
    {
      uint4 pk;
      pk.x = (uint32_t)f2bf(pfa.x) | ((uint32_t)f2bf(pfa.y) << 16);
      pk.y = (uint32_t)f2bf(pfa.z) | ((uint32_t)f2bf(pfa.w) << 16);
      pk.z = (uint32_t)f2bf(pfb.x) | ((uint32_t)f2bf(pfb.y) << 16);
      pk.w = (uint32_t)f2bf(pfb.z) | ((uint32_t)f2bf(pfb.w) << 16);
      *(uint4*)((char*)&xs_lds[(t + 1) & 1][0] + st_byte) = pk;
    }
    {
      const int tp = (t + 2 < TT) ? (t + 2) : (TT - 1);
      const size_t base = (size_t)(b0 + srow) * TT + tp;
      if (li < 15) { pfa = *(const float4*)(x + base * FF + li * 8);
                     pfb = *(const float4*)(x + base * FF + li * 8 + 4); }
      else         { pfa = *(const float4*)(x + base * FF + 120);
                     pfb = *(const float4*)(pa + base * 4); }
    }
  }

  __syncthreads();   // full drain; h_255 in h_lds[0], W1 block 255 in w1_lds[1] (t=254 dummy DMA)

  // W1 tail: wacc += h_255 * W1block(255)
  {
    const char* hb = (const char*)&h_lds[0][0];
    bf16x8 at0 = *(const bf16x8*)(hb + row16 * 128 + (((0 + kg) << 4) ^ swz));
    bf16x8 at1 = *(const bf16x8*)(hb + row16 * 128 + (((4 + kg) << 4) ^ swz));
    const char* wb = (const char*)&w1_lds[1][0] + w * 2048 + l * 16;
    bf16x8 ba = *(const bf16x8*)(wb);
    bf16x8 bb = *(const bf16x8*)(wb + 1024);
    wacc = MFMA16(at0, ba, wacc, 0, 0, 0);
    wacc = MFMA16(at1, bb, wacc, 0, 0, 0);
  }

  // MLP head
  {
    const int kcol = w * 16 + row16;
    const float bv = b1[kcol];
#pragma unroll
    for (int jj = 0; jj < 4; ++jj)
      mlp_a[(kg * 4 + jj) * 65 + kcol] = fmaxf(wacc[jj] + bv, 0.f);
  }
  __syncthreads();
  {
    const int b = tid >> 4, j0 = tid & 15;
    float s0 = b2[j0], s1 = b2[j0 + 16], s2 = b2[j0 + 32], s3 = b2[j0 + 48];
#pragma unroll 8
    for (int k = 0; k < 64; ++k) {
      const float av = mlp_a[b * 65 + k];
      s0 += av * w2_lds[k * 64 + j0];
      s1 += av * w2_lds[k * 64 + j0 + 16];
      s2 += av * w2_lds[k * 64 + j0 + 32];
      s3 += av * w2_lds[k * 64 + j0 + 48];
    }
    mlp_b[b * 65 + j0]      = fmaxf(s0, 0.f);
    mlp_b[b * 65 + j0 + 16] = fmaxf(s1, 0.f);
    mlp_b[b * 65 + j0 + 32] = fmaxf(s2, 0.f);
    mlp_b[b * 65 + j0 + 48] = fmaxf(s3, 0.f);
  }
  __syncthreads();
  if (tid < 128) {
    const int b = tid >> 3, jj = tid & 7;
    float s = b3[jj];
#pragma unroll 8
    for (int k = 0; k < 64; ++k) s += mlp_b[b * 65 + k] * W3[(size_t)k * 8 + jj];
    out[(size_t)(b0 + b) * 8 + jj] = s;
  }
}

// ---------------- fallback (R2 kernel, used only if ws_size too small) ----------------
__global__ __launch_bounds__(256, 1) void actor_fused_fb(
    const float* __restrict__ x,  const float* __restrict__ pa,
    const float* __restrict__ Wx, const float* __restrict__ Wh,
    const float* __restrict__ bg, const float* __restrict__ W1,
    const float* __restrict__ b1, const float* __restrict__ W2,
    const float* __restrict__ b2, const float* __restrict__ W3,
    const float* __restrict__ b3, float* __restrict__ out)
{
  __shared__ __align__(16) uint16_t xs_lds[2][BB * 128];
  __shared__ __align__(16) uint16_t h_lds[2][BB * HH];
  __shared__ float w2_lds[64 * 64];
  __shared__ float mlp_a[BB * 65];
  __shared__ float mlp_b[BB * 65];

  const int tid = threadIdx.x, w = tid >> 6, l = tid & 63;
  const int row16 = l & 15, kg = l >> 4;
  const int b0 = blockIdx.x * BB, swz = (row16 & 7) << 4;

  bf16x8 bwx[4][4], bwh[4][2];
  float bias4[4];
#pragma unroll
  for (int g = 0; g < 4; ++g) {
    const int col = g * 64 + w * 16 + row16;
    bias4[g] = bg[col];
#pragma unroll
    for (int kf = 0; kf < 4; ++kf)
#pragma unroll
      for (int j = 0; j < 8; ++j)
        bwx[g][kf][j] = (short)f2bf(Wx[(size_t)(kf * 32 + kg * 8 + j) * GG + col]);
#pragma unroll
    for (int kf = 0; kf < 2; ++kf)
#pragma unroll
      for (int j = 0; j < 8; ++j)
        bwh[g][kf][j] = (short)f2bf(Wh[(size_t)(kf * 32 + kg * 8 + j) * GG + col]);
  }
  for (int i = tid; i < 64 * 64; i += 256) w2_lds[i] = W2[i];
  reinterpret_cast<uint64_t*>(&h_lds[0][0])[tid] = 0ull;

  const int srow = tid >> 4, li = tid & 15;
  const int st_byte = srow * 256 + ((li << 4) ^ ((srow & 7) << 4));
  {
    const size_t base = (size_t)(b0 + srow) * TT + 0;
    float4 fa, fb;
    if (li < 15) { fa = *(const float4*)(x + base * FF + li * 8);
                   fb = *(const float4*)(x + base * FF + li * 8 + 4); }
    else         { fa = *(const float4*)(x + base * FF + 120);
                   fb = *(const float4*)(pa + base * 4); }
    uint4 pk;
    pk.x = (uint32_t)f2bf(fa.x) | ((uint32_t)f2bf(fa.y) << 16);
    pk.y = (uint32_t)f2bf(fa.z) | ((uint32_t)f2bf(fa.w) << 16);
    pk.z = (uint32_t)f2bf(fb.x) | ((uint32_t)f2bf(fb.y) << 16);
    pk.w = (uint32_t)f2bf(fb.z) | ((uint32_t)f2bf(fb.w) << 16);
    *(uint4*)((char*)&xs_lds[0][0] + st_byte) = pk;
  }
  float4 pfa, pfb;
  {
    const size_t base = (size_t)(b0 + srow) * TT + 1;
    if (li < 15) { pfa = *(const float4*)(x + base * FF + li * 8);
                   pfb = *(const float4*)(x + base * FF + li * 8 + 4); }
    else         { pfa = *(const float4*)(x + base * FF + 120);
                   pfb = *(const float4*)(pa + base * 4); }
  }
  __syncthreads();

  f32x4 cacc = {0.f, 0.f, 0.f, 0.f};
  f32x4 wacc = {0.f, 0.f, 0.f, 0.f};
  int cur = 0;

  for (int t = 0; t < TT; ++t) {
    {
      uint4 pk;
      pk.x = (uint32_t)f2bf(pfa.x) | ((uint32_t)f2bf(pfa.y) << 16);
      pk.y = (uint32_t)f2bf(pfa.z) | ((uint32_t)f2bf(pfa.w) << 16);
      pk.z = (uint32_t)f2bf(pfb.x) | ((uint32_t)f2bf(pfb.y) << 16);
      pk.w = (uint32_t)f2bf(pfb.z) | ((uint32_t)f2bf(pfb.w) << 16);
      *(uint4*)((char*)&xs_lds[cur ^ 1][0] + st_byte) = pk;
    }
    {
      const int tp = (t + 2 < TT) ? (t + 2) : (TT - 1);
      const size_t base = (size_t)(b0 + srow) * TT + tp;
      if (li < 15) { pfa = *(const float4*)(x + base * FF + li * 8);
                     pfb = *(const float4*)(x + base * FF + li * 8 + 4); }
      else         { pfa = *(const float4*)(x + base * FF + 120);
                     pfb = *(const float4*)(pa + base * 4); }
    }
    bf16x8 bw1a, bw1b;
    if (t > 0) {
      const size_t r0 = (size_t)(t - 1) * 64 + kg * 8;
      const int c1w = w * 16 + row16;
#pragma unroll
      for (int j = 0; j < 8; ++j) {
        bw1a[j] = (short)f2bf(W1[(r0 + j) * 64 + c1w]);
        bw1b[j] = (short)f2bf(W1[(r0 + 32 + j) * 64 + c1w]);
      }
    }
    const char* xb = (const char*)&xs_lds[cur][0];
    const char* hb = (const char*)&h_lds[cur][0];
    bf16x8 ax0 = *(const bf16x8*)(xb + row16 * 256 + (((0 * 4 + kg) << 4) ^ swz));
    bf16x8 ax1 = *(const bf16x8*)(xb + row16 * 256 + (((1 * 4 + kg) << 4) ^ swz));
    bf16x8 ax2 = *(const bf16x8*)(xb + row16 * 256 + (((2 * 4 + kg) << 4) ^ swz));
    bf16x8 ax3 = *(const bf16x8*)(xb + row16 * 256 + (((3 * 4 + kg) << 4) ^ swz));
    bf16x8 ah0 = *(const bf16x8*)(hb + row16 * 128 + (((0 + kg) << 4) ^ swz));
    bf16x8 ah1 = *(const bf16x8*)(hb + row16 * 128 + (((4 + kg) << 4) ^ swz));

    f32x4 g0 = {bias4[0], bias4[0], bias4[0], bias4[0]};
    f32x4 g1 = {bias4[1], bias4[1], bias4[1], bias4[1]};
    f32x4 g2 = {bias4[2], bias4[2], bias4[2], bias4[2]};
    f32x4 g3 = {bias4[3], bias4[3], bias4[3], bias4[3]};
    g0 = MFMA16(ax0, bwx[0][0], g0, 0, 0, 0);
    g1 = MFMA16(ax0, bwx[1][0], g1, 0, 0, 0);
    g2 = MFMA16(ax0, bwx[2][0], g2, 0, 0, 0);
    g3 = MFMA16(ax0, bwx[3][0], g3, 0, 0, 0);
    g0 = MFMA16(ax1, bwx[0][1], g0, 0, 0, 0);
    g1 = MFMA16(ax1, bwx[1][1], g1, 0, 0, 0);
    g2 = MFMA16(ax1, bwx[2][1], g2, 0, 0, 0);
    g3 = MFMA16(ax1, bwx[3][1], g3, 0, 0, 0);
    g0 = MFMA16(ax2, bwx[0][2], g0, 0, 0, 0);
    g1 = MFMA16(ax2, bwx[1][2], g1, 0, 0, 0);
    g2 = MFMA16(ax2, bwx[2][2], g2, 0, 0, 0);
    g3 = MFMA16(ax2, bwx[3][2], g3, 0, 0, 0);
    g0 = MFMA16(ax3, bwx[0][3], g0, 0, 0, 0);
    g1 = MFMA16(ax3, bwx[1][3], g1, 0, 0, 0);
    g2 = MFMA16(ax3, bwx[2][3], g2, 0, 0, 0);
    g3 = MFMA16(ax3, bwx[3][3], g3, 0, 0, 0);
    g0 = MFMA16(ah0, bwh[0][0], g0, 0, 0, 0);
    g1 = MFMA16(ah0, bwh[1][0], g1, 0, 0, 0);
    g2 = MFMA16(ah0, bwh[2][0], g2, 0, 0, 0);
    g3 = MFMA16(ah0, bwh[3][0], g3, 0, 0, 0);
    g0 = MFMA16(ah1, bwh[0][1], g0, 0, 0, 0);
    g1 = MFMA16(ah1, bwh[1][1], g1, 0, 0, 0);
    g2 = MFMA16(ah1, bwh[2][1], g2, 0, 0, 0);
    g3 = MFMA16(ah1, bwh[3][1], g3, 0, 0, 0);
    if (t > 0) {
      wacc = MFMA16(ah0, bw1a, wacc, 0, 0, 0);
      wacc = MFMA16(ah1, bw1b, wacc, 0, 0, 0);
    }
    const int kcol = w * 16 + row16;
#pragma unroll
    for (int jj = 0; jj < 4; ++jj) {
      float i_ = fsig(g0[jj]);
      float f_ = fsig(g1[jj]);
      float gv = ftanh(g2[jj]);
      float o_ = fsig(g3[jj]);
      float cn = f_ * cacc[jj] + i_ * gv;
      cacc[jj] = cn;
      float hv = o_ * ftanh(cn);
      const int row = kg * 4 + jj;
      *(uint16_t*)((char*)&h_lds[cur ^ 1][0] + row * 128 +
                   (((kcol >> 3) << 4) ^ ((row & 7) << 4)) + (kcol & 7) * 2) = f2bf(hv);
      if (t == TT - 1) {
        out[C_OFF + (size_t)(b0 + row) * HH + kcol] = cn;
        out[H_OFF + (size_t)(b0 + row) * HH + kcol] = hv;
      }
    }
    __syncthreads();
    cur ^= 1;
  }
  {
    const char* hb = (const char*)&h_lds[cur][0];
    bf16x8 at0 = *(const bf16x8*)(hb + row16 * 128 + (((0 + kg) << 4) ^ swz));
    bf16x8 at1 = *(const bf16x8*)(hb + row16 * 128 + (((4 + kg) << 4) ^ swz));
    bf16x8 bw1a, bw1b;
    const size_t r0 = (size_t)(TT - 1) * 64 + kg * 8;
    const int c1w = w * 16 + row16;
#pragma unroll
    for (int j = 0; j < 8; ++j) {
      bw1a[j] = (short)f2bf(W1[(r0 + j) * 64 + c1w]);
      bw1b[j] = (short)f2bf(W1[(r0 + 32 + j) * 64 + c1w]);
    }
    wacc = MFMA16(at0, bw1a, wacc, 0, 0, 0);
    wacc = MFMA16(at1, bw1b, wacc, 0, 0, 0);
  }
  {
    const int kcol = w * 16 + row16;
    const float bv = b1[kcol];
#pragma unroll
    for (int jj = 0; jj < 4; ++jj)
      mlp_a[(kg * 4 + jj) * 65 + kcol] = fmaxf(wacc[jj] + bv, 0.f);
  }
  __syncthreads();
  {
    const int b = tid >> 4, j0 = tid & 15;
    float s0 = b2[j0], s1 = b2[j0 + 16], s2 = b2[j0 + 32], s3 = b2[j0 + 48];
#pragma unroll 8
    for (int k = 0; k < 64; ++k) {
      const float av = mlp_a[b * 65 + k];
      s0 += av * w2_lds[k * 64 + j0];
      s1 += av * w2_lds[k * 64 + j0 + 16];
      s2 += av * w2_lds[k * 64 + j0 + 32];
      s3 += av * w2_lds[k * 64 + j0 + 48];
    }
    mlp_b[b * 65 + j0]      = fmaxf(s0, 0.f);
    mlp_b[b * 65 + j0 + 16] = fmaxf(s1, 0.f);
    mlp_b[b * 65 + j0 + 32] = fmaxf(s2, 0.f);
    mlp_b[b * 65 + j0 + 48] = fmaxf(s3, 0.f);
  }
  __syncthreads();
  if (tid < 128) {
    const int b = tid >> 3, jj = tid & 7;
    float s = b3[jj];
#pragma unroll 8
    for (int k = 0; k < 64; ++k) s += mlp_b[b * 65 + k] * W3[(size_t)k * 8 + jj];
    out[(size_t)(b0 + b) * 8 + jj] = s;
  }
}

extern "C" void kernel_launch(void* const* d_in, const int* in_sizes, int n_in,
                              void* d_out, int out_size, void* d_ws, size_t ws_size,
                              hipStream_t stream) {
  const float* x  = (const float*)d_in[0];
  const float* pa = (const float*)d_in[1];
  const float* Wx = (const float*)d_in[2];
  const float* Wh = (const float*)d_in[3];
  const float* bg = (const float*)d_in[4];
  const float* W1 = (const float*)d_in[5];
  const float* b1 = (const float*)d_in[6];
  const float* W2 = (const float*)d_in[7];
  const float* b2 = (const float*)d_in[8];
  const float* W3 = (const float*)d_in[9];
  const float* b3 = (const float*)d_in[10];
  (void)in_sizes; (void)n_in; (void)out_size;

  if (ws_size >= WS_NEED) {
    uint16_t* wsp = (uint16_t*)d_ws;
    pack_weights<<<dim3(536), dim3(256), 0, stream>>>(Wx, Wh, W1, wsp);
    actor_lstm<<<dim3(Bsz / BB), dim3(256), 0, stream>>>(
        x, pa, bg, wsp, b1, W2, b2, W3, b3, (float*)d_out);
  } else {
    actor_fused_fb<<<dim3(Bsz / BB), dim3(256), 0, stream>>>(
        x, pa, Wx, Wh, bg, W1, b1, W2, b2, W3, b3, (float*)d_out);
  }
}

// Round 4
// 273.305 us; speedup vs baseline: 1.9031x; 1.9031x over previous
//
#include <hip/hip_runtime.h>
#include <hip/hip_bf16.h>
#include <stdint.h>

static constexpr int Bsz = 1024;
static constexpr int TT  = 256;
static constexpr int FF  = 124;
static constexpr int HH  = 64;
static constexpr int GG  = 256;   // 4*H
static constexpr int BB  = 16;    // batch rows per block
static constexpr int C_OFF = Bsz * 8;
static constexpr int H_OFF = C_OFF + Bsz * HH;

// packed-weight workspace layout (uint16_t units)
static constexpr int WXH_U16 = 24 * 256 * 8;      // 49152   (Wx/Wh frags)
static constexpr int W1P_U16 = 256 * 4096;        // 1048576 (W1 frags, 256 blocks x 8KB)
static constexpr size_t WS_NEED = (size_t)(WXH_U16 + W1P_U16) * 2;  // ~2.1 MB

typedef __attribute__((ext_vector_type(8))) short bf16x8;
typedef __attribute__((ext_vector_type(4))) float f32x4;

#define MFMA16 __builtin_amdgcn_mfma_f32_16x16x32_bf16

__device__ __forceinline__ uint16_t f2bf(float x) {
  union { float f; uint32_t u; } v; v.f = x;
  return (uint16_t)((v.u + 0x7FFFu + ((v.u >> 16) & 1u)) >> 16);
}
__device__ __forceinline__ float fsig(float x) {
  return __builtin_amdgcn_rcpf(1.0f + __builtin_amdgcn_exp2f(-1.4426950408889634f * x));
}
__device__ __forceinline__ float ftanh(float x) {
  float e = __builtin_amdgcn_exp2f(-2.8853900817779268f * x);
  return (1.0f - e) * __builtin_amdgcn_rcpf(1.0f + e);
}
__device__ __forceinline__ bf16x8 cvt8(float4 a, float4 b) {
  bf16x8 r;
  r[0] = (short)f2bf(a.x); r[1] = (short)f2bf(a.y);
  r[2] = (short)f2bf(a.z); r[3] = (short)f2bf(a.w);
  r[4] = (short)f2bf(b.x); r[5] = (short)f2bf(b.y);
  r[6] = (short)f2bf(b.z); r[7] = (short)f2bf(b.w);
  return r;
}

// ---------------- pre-pass: pack Wx/Wh/W1 into bf16 fragment order ----------------
__global__ __launch_bounds__(256) void pack_weights(
    const float* __restrict__ Wx, const float* __restrict__ Wh,
    const float* __restrict__ W1, uint16_t* __restrict__ wsp)
{
  const int c = blockIdx.x * 256 + threadIdx.x;
  uint16_t v[8];
  size_t dst;
  if (c < 6144) {                       // Wx/Wh frags: [f 0..23][tid 0..255][8]
    const int f = c >> 8, tid = c & 255;
    const int w = tid >> 6, l = tid & 63;
    const int kgl = (l >> 4) * 8, r16 = l & 15;
    if (f < 16) {
      const int g = f >> 2, kf = f & 3;
      const int col = g * 64 + w * 16 + r16;
#pragma unroll
      for (int j = 0; j < 8; ++j) v[j] = f2bf(Wx[(size_t)(kf * 32 + kgl + j) * GG + col]);
    } else {
      const int g = (f - 16) >> 1, kf = (f - 16) & 1;
      const int col = g * 64 + w * 16 + r16;
#pragma unroll
      for (int j = 0; j < 8; ++j) v[j] = f2bf(Wh[(size_t)(kf * 32 + kgl + j) * GG + col]);
    }
    dst = (size_t)c * 8;
  } else if (c < 6144 + 131072) {       // W1 frags: [t][w][half][l][8]
    const int cc = c - 6144;
    const int t = cc >> 9, r = cc & 511;
    const int w = r >> 7, half = (r >> 6) & 1, l = r & 63;
    const int row0 = t * 64 + half * 32 + (l >> 4) * 8;
    const int col = w * 16 + (l & 15);
#pragma unroll
    for (int j = 0; j < 8; ++j) v[j] = f2bf(W1[(size_t)(row0 + j) * 64 + col]);
    dst = (size_t)WXH_U16 + (size_t)cc * 8;
  } else return;
  uint4 pk;
  pk.x = (uint32_t)v[0] | ((uint32_t)v[1] << 16);
  pk.y = (uint32_t)v[2] | ((uint32_t)v[3] << 16);
  pk.z = (uint32_t)v[4] | ((uint32_t)v[5] << 16);
  pk.w = (uint32_t)v[6] | ((uint32_t)v[7] << 16);
  *(uint4*)(wsp + dst) = pk;
}

// ---------------- main kernel: producer/consumer wave specialization ----------------

// producer: load x/pa for step tl into stage regs (8 x float4)
#define PROD_LOAD(SS, tl) { \
  const size_t rbase = (size_t)(b0 + row16) * TT + (tl); \
  const float* xr = x + rbase * FF; \
  _Pragma("unroll") \
  for (int kf = 0; kf < 4; ++kf) { \
    const int c0 = kf * 32 + kg * 8; \
    SS[kf * 2]     = *(const float4*)(xr + c0); \
    SS[kf * 2 + 1] = (c0 == 120) ? *(const float4*)(pa + rbase * 4) \
                                 : *(const float4*)(xr + c0 + 4); \
  } }

// producer: xproj tile from stage regs -> ring slot (bias folded)
#define PROD_COMPUTE(SS, slotw) { \
  bf16x8 ax0 = cvt8(SS[0], SS[1]); \
  bf16x8 ax1 = cvt8(SS[2], SS[3]); \
  bf16x8 ax2 = cvt8(SS[4], SS[5]); \
  bf16x8 ax3 = cvt8(SS[6], SS[7]); \
  float* rw = xp_ring + (slotw) * 4096 + pw * 1024 + l * 4; \
  _Pragma("unroll") \
  for (int g = 0; g < 4; ++g) { \
    f32x4 acc = {bias4[g], bias4[g], bias4[g], bias4[g]}; \
    acc = MFMA16(ax0, bwx[g][0], acc, 0, 0, 0); \
    acc = MFMA16(ax1, bwx[g][1], acc, 0, 0, 0); \
    acc = MFMA16(ax2, bwx[g][2], acc, 0, 0, 0); \
    acc = MFMA16(ax3, bwx[g][3], acc, 0, 0, 0); \
    *(f32x4*)(rw + g * 256) = acc; \
  } }

// consumer: one recurrence step
#define CONS_STEP(p, PAR) { \
  const uint16_t* w1p = wsp + (size_t)WXH_U16 + ((size_t)(p) * 512 + w * 128 + l) * 8; \
  bf16x8 nw1a = *(const bf16x8*)(w1p); \
  bf16x8 nw1b = *(const bf16x8*)(w1p + 512); \
  const int slot_r = (p) % 3; \
  const float* rb = xp_ring + slot_r * 4096 + w * 1024 + l * 4; \
  f32x4 a0 = *(const f32x4*)(rb); \
  f32x4 a1 = *(const f32x4*)(rb + 256); \
  f32x4 a2 = *(const f32x4*)(rb + 512); \
  f32x4 a3 = *(const f32x4*)(rb + 768); \
  const char* hb = (const char*)&hbuf[PAR][0]; \
  bf16x8 ah0 = *(const bf16x8*)(hb + row16 * 128 + (((0 + kg) << 4) ^ swz)); \
  bf16x8 ah1 = *(const bf16x8*)(hb + row16 * 128 + (((4 + kg) << 4) ^ swz)); \
  a0 = MFMA16(ah0, bwh[0][0], a0, 0, 0, 0); \
  a1 = MFMA16(ah0, bwh[1][0], a1, 0, 0, 0); \
  a2 = MFMA16(ah0, bwh[2][0], a2, 0, 0, 0); \
  a3 = MFMA16(ah0, bwh[3][0], a3, 0, 0, 0); \
  a0 = MFMA16(ah1, bwh[0][1], a0, 0, 0, 0); \
  a1 = MFMA16(ah1, bwh[1][1], a1, 0, 0, 0); \
  a2 = MFMA16(ah1, bwh[2][1], a2, 0, 0, 0); \
  a3 = MFMA16(ah1, bwh[3][1], a3, 0, 0, 0); \
  wacc = MFMA16(ah0, cw1a, wacc, 0, 0, 0); \
  wacc = MFMA16(ah1, cw1b, wacc, 0, 0, 0); \
  _Pragma("unroll") \
  for (int jj = 0; jj < 4; ++jj) { \
    float i_ = fsig(a0[jj]); \
    float f_ = fsig(a1[jj]); \
    float gv = ftanh(a2[jj]); \
    float o_ = fsig(a3[jj]); \
    float cn = f_ * cacc[jj] + i_ * gv; \
    cacc[jj] = cn; \
    float hv = o_ * ftanh(cn); \
    const int row = kg * 4 + jj; \
    *(uint16_t*)((char*)&hbuf[(PAR) ^ 1][0] + row * 128 + \
                 (((kcol >> 3) << 4) ^ ((row & 7) << 4)) + (kcol & 7) * 2) = f2bf(hv); \
    if ((p) == TT - 1) { \
      out[C_OFF + (size_t)(b0 + row) * HH + kcol] = cn; \
      out[H_OFF + (size_t)(b0 + row) * HH + kcol] = hv; \
    } \
  } \
  cw1a = nw1a; cw1b = nw1b; }

#define PERIOD(p, SS, PAR) { \
  if (w < 4) { CONS_STEP(p, PAR); } \
  else { \
    PROD_COMPUTE(SS, ((p) + 2) % 3); \
    const int tl = ((p) + 4 < TT) ? (p) + 4 : TT - 1; \
    PROD_LOAD(SS, tl); \
  } \
  asm volatile("s_waitcnt lgkmcnt(0)\n\ts_barrier" ::: "memory"); }

__global__ __launch_bounds__(512, 1) void actor_pc(
    const float* __restrict__ x,  const float* __restrict__ pa,
    const float* __restrict__ bg, const uint16_t* __restrict__ wsp,
    const float* __restrict__ b1, const float* __restrict__ W2,
    const float* __restrict__ b2, const float* __restrict__ W3,
    const float* __restrict__ b3, float* __restrict__ out)
{
  __shared__ __align__(16) float xp_ring[3 * 4096];   // 48 KB, [slot][w][g][lane][4]
  __shared__ __align__(16) uint16_t hbuf[2][1024];    // 4 KB, swizzled bf16
  __shared__ float w2_lds[4096];                      // 16 KB
  __shared__ float mlp_a[16 * 65];
  __shared__ float mlp_b[16 * 65];

  const int tid   = threadIdx.x;
  const int w     = tid >> 6;     // 0..3 consumer (k-slice), 4..7 producer
  const int pw    = w & 3;
  const int l     = tid & 63;
  const int row16 = l & 15;
  const int kg    = l >> 4;
  const int b0    = blockIdx.x * BB;
  const int swz   = (row16 & 7) << 4;
  const int kcol  = pw * 16 + row16;

  // role-specific persistent fragments
  bf16x8 bwx[4][4];
  bf16x8 bwh[4][2];
  float bias4[4];
  if (w >= 4) {
#pragma unroll
    for (int g = 0; g < 4; ++g) {
#pragma unroll
      for (int kf = 0; kf < 4; ++kf)
        bwx[g][kf] = *(const bf16x8*)(wsp + ((size_t)(g * 4 + kf) * 256 + pw * 64 + l) * 8);
      bias4[g] = bg[g * 64 + pw * 16 + row16];
    }
  } else {
#pragma unroll
    for (int g = 0; g < 4; ++g)
#pragma unroll
      for (int kf = 0; kf < 2; ++kf)
        bwh[g][kf] = *(const bf16x8*)(wsp + ((size_t)(16 + g * 2 + kf) * 256 + w * 64 + l) * 8);
  }

  for (int i = tid; i < 4096; i += 512) w2_lds[i] = W2[i];
  if (tid < 256) reinterpret_cast<uint64_t*>(&hbuf[0][0])[tid] = 0ull;  // h_{-1}=0

  float4 S0[8], S1[8];
  bf16x8 cw1a = {}, cw1b = {};
  f32x4 cacc = {0.f, 0.f, 0.f, 0.f};
  f32x4 wacc = {0.f, 0.f, 0.f, 0.f};

  // prologue
  if (w >= 4) { PROD_LOAD(S0, 0); PROD_LOAD(S1, 1); }
  else {
    const uint16_t* w1p = wsp + (size_t)WXH_U16 + ((size_t)w * 128 + l) * 8;  // block 0
    cw1a = *(const bf16x8*)(w1p);
    cw1b = *(const bf16x8*)(w1p + 512);
  }
  // preA (period -2): xproj(0) -> slot 0; load x(2) -> S0
  if (w >= 4) { PROD_COMPUTE(S0, 0); PROD_LOAD(S0, 2); }
  asm volatile("s_waitcnt lgkmcnt(0)\n\ts_barrier" ::: "memory");
  // preB (period -1): xproj(1) -> slot 1; load x(3) -> S1
  if (w >= 4) { PROD_COMPUTE(S1, 1); PROD_LOAD(S1, 3); }
  asm volatile("s_waitcnt lgkmcnt(0)\n\ts_barrier" ::: "memory");

#pragma unroll 1
  for (int p = 0; p < TT; p += 2) {
    PERIOD(p, S0, 0);
    PERIOD(p + 1, S1, 1);
  }

  __syncthreads();   // full drain; h_255 in hbuf[0]; cw1 = W1 block 255

  if (w < 4) {
    const char* hb = (const char*)&hbuf[0][0];
    bf16x8 at0 = *(const bf16x8*)(hb + row16 * 128 + (((0 + kg) << 4) ^ swz));
    bf16x8 at1 = *(const bf16x8*)(hb + row16 * 128 + (((4 + kg) << 4) ^ swz));
    wacc = MFMA16(at0, cw1a, wacc, 0, 0, 0);
    wacc = MFMA16(at1, cw1b, wacc, 0, 0, 0);
    const float bv = b1[kcol];
#pragma unroll
    for (int jj = 0; jj < 4; ++jj)
      mlp_a[(kg * 4 + jj) * 65 + kcol] = fmaxf(wacc[jj] + bv, 0.f);
  }
  __syncthreads();
  {  // MLP layer 2: 512 threads, 16x64 outputs
    const int b = tid >> 5, j0 = tid & 31;
    float s0 = b2[j0], s1 = b2[j0 + 32];
#pragma unroll 8
    for (int k = 0; k < 64; ++k) {
      const float av = mlp_a[b * 65 + k];
      s0 += av * w2_lds[k * 64 + j0];
      s1 += av * w2_lds[k * 64 + j0 + 32];
    }
    mlp_b[b * 65 + j0]      = fmaxf(s0, 0.f);
    mlp_b[b * 65 + j0 + 32] = fmaxf(s1, 0.f);
  }
  __syncthreads();
  if (tid < 128) {  // MLP layer 3: 16x8 outputs
    const int b = tid >> 3, jj = tid & 7;
    float s = b3[jj];
#pragma unroll 8
    for (int k = 0; k < 64; ++k) s += mlp_b[b * 65 + k] * W3[(size_t)k * 8 + jj];
    out[(size_t)(b0 + b) * 8 + jj] = s;
  }
}

// ---------------- fallback (R2 kernel, used only if ws_size too small) ----------------
__global__ __launch_bounds__(256, 1) void actor_fused_fb(
    const float* __restrict__ x,  const float* __restrict__ pa,
    const float* __restrict__ Wx, const float* __restrict__ Wh,
    const float* __restrict__ bg, const float* __restrict__ W1,
    const float* __restrict__ b1, const float* __restrict__ W2,
    const float* __restrict__ b2, const float* __restrict__ W3,
    const float* __restrict__ b3, float* __restrict__ out)
{
  __shared__ __align__(16) uint16_t xs_lds[2][BB * 128];
  __shared__ __align__(16) uint16_t h_lds[2][BB * HH];
  __shared__ float w2_lds[64 * 64];
  __shared__ float mlp_a[BB * 65];
  __shared__ float mlp_b[BB * 65];

  const int tid = threadIdx.x, w = tid >> 6, l = tid & 63;
  const int row16 = l & 15, kg = l >> 4;
  const int b0 = blockIdx.x * BB, swz = (row16 & 7) << 4;

  bf16x8 bwx[4][4], bwh[4][2];
  float bias4[4];
#pragma unroll
  for (int g = 0; g < 4; ++g) {
    const int col = g * 64 + w * 16 + row16;
    bias4[g] = bg[col];
#pragma unroll
    for (int kf = 0; kf < 4; ++kf)
#pragma unroll
      for (int j = 0; j < 8; ++j)
        bwx[g][kf][j] = (short)f2bf(Wx[(size_t)(kf * 32 + kg * 8 + j) * GG + col]);
#pragma unroll
    for (int kf = 0; kf < 2; ++kf)
#pragma unroll
      for (int j = 0; j < 8; ++j)
        bwh[g][kf][j] = (short)f2bf(Wh[(size_t)(kf * 32 + kg * 8 + j) * GG + col]);
  }
  for (int i = tid; i < 64 * 64; i += 256) w2_lds[i] = W2[i];
  reinterpret_cast<uint64_t*>(&h_lds[0][0])[tid] = 0ull;

  const int srow = tid >> 4, li = tid & 15;
  const int st_byte = srow * 256 + ((li << 4) ^ ((srow & 7) << 4));
  {
    const size_t base = (size_t)(b0 + srow) * TT + 0;
    float4 fa, fb;
    if (li < 15) { fa = *(const float4*)(x + base * FF + li * 8);
                   fb = *(const float4*)(x + base * FF + li * 8 + 4); }
    else         { fa = *(const float4*)(x + base * FF + 120);
                   fb = *(const float4*)(pa + base * 4); }
    uint4 pk;
    pk.x = (uint32_t)f2bf(fa.x) | ((uint32_t)f2bf(fa.y) << 16);
    pk.y = (uint32_t)f2bf(fa.z) | ((uint32_t)f2bf(fa.w) << 16);
    pk.z = (uint32_t)f2bf(fb.x) | ((uint32_t)f2bf(fb.y) << 16);
    pk.w = (uint32_t)f2bf(fb.z) | ((uint32_t)f2bf(fb.w) << 16);
    *(uint4*)((char*)&xs_lds[0][0] + st_byte) = pk;
  }
  float4 pfa, pfb;
  {
    const size_t base = (size_t)(b0 + srow) * TT + 1;
    if (li < 15) { pfa = *(const float4*)(x + base * FF + li * 8);
                   pfb = *(const float4*)(x + base * FF + li * 8 + 4); }
    else         { pfa = *(const float4*)(x + base * FF + 120);
                   pfb = *(const float4*)(pa + base * 4); }
  }
  __syncthreads();

  f32x4 cacc = {0.f, 0.f, 0.f, 0.f};
  f32x4 wacc = {0.f, 0.f, 0.f, 0.f};
  int cur = 0;

  for (int t = 0; t < TT; ++t) {
    {
      uint4 pk;
      pk.x = (uint32_t)f2bf(pfa.x) | ((uint32_t)f2bf(pfa.y) << 16);
      pk.y = (uint32_t)f2bf(pfa.z) | ((uint32_t)f2bf(pfa.w) << 16);
      pk.z = (uint32_t)f2bf(pfb.x) | ((uint32_t)f2bf(pfb.y) << 16);
      pk.w = (uint32_t)f2bf(pfb.z) | ((uint32_t)f2bf(pfb.w) << 16);
      *(uint4*)((char*)&xs_lds[cur ^ 1][0] + st_byte) = pk;
    }
    {
      const int tp = (t + 2 < TT) ? (t + 2) : (TT - 1);
      const size_t base = (size_t)(b0 + srow) * TT + tp;
      if (li < 15) { pfa = *(const float4*)(x + base * FF + li * 8);
                     pfb = *(const float4*)(x + base * FF + li * 8 + 4); }
      else         { pfa = *(const float4*)(x + base * FF + 120);
                     pfb = *(const float4*)(pa + base * 4); }
    }
    bf16x8 bw1a, bw1b;
    if (t > 0) {
      const size_t r0 = (size_t)(t - 1) * 64 + kg * 8;
      const int c1w = w * 16 + row16;
#pragma unroll
      for (int j = 0; j < 8; ++j) {
        bw1a[j] = (short)f2bf(W1[(r0 + j) * 64 + c1w]);
        bw1b[j] = (short)f2bf(W1[(r0 + 32 + j) * 64 + c1w]);
      }
    }
    const char* xb = (const char*)&xs_lds[cur][0];
    const char* hb = (const char*)&h_lds[cur][0];
    bf16x8 ax0 = *(const bf16x8*)(xb + row16 * 256 + (((0 * 4 + kg) << 4) ^ swz));
    bf16x8 ax1 = *(const bf16x8*)(xb + row16 * 256 + (((1 * 4 + kg) << 4) ^ swz));
    bf16x8 ax2 = *(const bf16x8*)(xb + row16 * 256 + (((2 * 4 + kg) << 4) ^ swz));
    bf16x8 ax3 = *(const bf16x8*)(xb + row16 * 256 + (((3 * 4 + kg) << 4) ^ swz));
    bf16x8 ah0 = *(const bf16x8*)(hb + row16 * 128 + (((0 + kg) << 4) ^ swz));
    bf16x8 ah1 = *(const bf16x8*)(hb + row16 * 128 + (((4 + kg) << 4) ^ swz));

    f32x4 g0 = {bias4[0], bias4[0], bias4[0], bias4[0]};
    f32x4 g1 = {bias4[1], bias4[1], bias4[1], bias4[1]};
    f32x4 g2 = {bias4[2], bias4[2], bias4[2], bias4[2]};
    f32x4 g3 = {bias4[3], bias4[3], bias4[3], bias4[3]};
    g0 = MFMA16(ax0, bwx[0][0], g0, 0, 0, 0);
    g1 = MFMA16(ax0, bwx[1][0], g1, 0, 0, 0);
    g2 = MFMA16(ax0, bwx[2][0], g2, 0, 0, 0);
    g3 = MFMA16(ax0, bwx[3][0], g3, 0, 0, 0);
    g0 = MFMA16(ax1, bwx[0][1], g0, 0, 0, 0);
    g1 = MFMA16(ax1, bwx[1][1], g1, 0, 0, 0);
    g2 = MFMA16(ax1, bwx[2][1], g2, 0, 0, 0);
    g3 = MFMA16(ax1, bwx[3][1], g3, 0, 0, 0);
    g0 = MFMA16(ax2, bwx[0][2], g0, 0, 0, 0);
    g1 = MFMA16(ax2, bwx[1][2], g1, 0, 0, 0);
    g2 = MFMA16(ax2, bwx[2][2], g2, 0, 0, 0);
    g3 = MFMA16(ax2, bwx[3][2], g3, 0, 0, 0);
    g0 = MFMA16(ax3, bwx[0][3], g0, 0, 0, 0);
    g1 = MFMA16(ax3, bwx[1][3], g1, 0, 0, 0);
    g2 = MFMA16(ax3, bwx[2][3], g2, 0, 0, 0);
    g3 = MFMA16(ax3, bwx[3][3], g3, 0, 0, 0);
    g0 = MFMA16(ah0, bwh[0][0], g0, 0, 0, 0);
    g1 = MFMA16(ah0, bwh[1][0], g1, 0, 0, 0);
    g2 = MFMA16(ah0, bwh[2][0], g2, 0, 0, 0);
    g3 = MFMA16(ah0, bwh[3][0], g3, 0, 0, 0);
    g0 = MFMA16(ah1, bwh[0][1], g0, 0, 0, 0);
    g1 = MFMA16(ah1, bwh[1][1], g1, 0, 0, 0);
    g2 = MFMA16(ah1, bwh[2][1], g2, 0, 0, 0);
    g3 = MFMA16(ah1, bwh[3][1], g3, 0, 0, 0);
    if (t > 0) {
      wacc = MFMA16(ah0, bw1a, wacc, 0, 0, 0);
      wacc = MFMA16(ah1, bw1b, wacc, 0, 0, 0);
    }
    const int kcol = w * 16 + row16;
#pragma unroll
    for (int jj = 0; jj < 4; ++jj) {
      float i_ = fsig(g0[jj]);
      float f_ = fsig(g1[jj]);
      float gv = ftanh(g2[jj]);
      float o_ = fsig(g3[jj]);
      float cn = f_ * cacc[jj] + i_ * gv;
      cacc[jj] = cn;
      float hv = o_ * ftanh(cn);
      const int row = kg * 4 + jj;
      *(uint16_t*)((char*)&h_lds[cur ^ 1][0] + row * 128 +
                   (((kcol >> 3) << 4) ^ ((row & 7) << 4)) + (kcol & 7) * 2) = f2bf(hv);
      if (t == TT - 1) {
        out[C_OFF + (size_t)(b0 + row) * HH + kcol] = cn;
        out[H_OFF + (size_t)(b0 + row) * HH + kcol] = hv;
      }
    }
    __syncthreads();
    cur ^= 1;
  }
  {
    const char* hb = (const char*)&h_lds[cur][0];
    bf16x8 at0 = *(const bf16x8*)(hb + row16 * 128 + (((0 + kg) << 4) ^ swz));
    bf16x8 at1 = *(const bf16x8*)(hb + row16 * 128 + (((4 + kg) << 4) ^ swz));
    bf16x8 bw1a, bw1b;
    const size_t r0 = (size_t)(TT - 1) * 64 + kg * 8;
    const int c1w = w * 16 + row16;
#pragma unroll
    for (int j = 0; j < 8; ++j) {
      bw1a[j] = (short)f2bf(W1[(r0 + j) * 64 + c1w]);
      bw1b[j] = (short)f2bf(W1[(r0 + 32 + j) * 64 + c1w]);
    }
    wacc = MFMA16(at0, bw1a, wacc, 0, 0, 0);
    wacc = MFMA16(at1, bw1b, wacc, 0, 0, 0);
  }
  {
    const int kcol = w * 16 + row16;
    const float bv = b1[kcol];
#pragma unroll
    for (int jj = 0; jj < 4; ++jj)
      mlp_a[(kg * 4 + jj) * 65 + kcol] = fmaxf(wacc[jj] + bv, 0.f);
  }
  __syncthreads();
  {
    const int b = tid >> 4, j0 = tid & 15;
    float s0 = b2[j0], s1 = b2[j0 + 16], s2 = b2[j0 + 32], s3 = b2[j0 + 48];
#pragma unroll 8
    for (int k = 0; k < 64; ++k) {
      const float av = mlp_a[b * 65 + k];
      s0 += av * w2_lds[k * 64 + j0];
      s1 += av * w2_lds[k * 64 + j0 + 16];
      s2 += av * w2_lds[k * 64 + j0 + 32];
      s3 += av * w2_lds[k * 64 + j0 + 48];
    }
    mlp_b[b * 65 + j0]      = fmaxf(s0, 0.f);
    mlp_b[b * 65 + j0 + 16] = fmaxf(s1, 0.f);
    mlp_b[b * 65 + j0 + 32] = fmaxf(s2, 0.f);
    mlp_b[b * 65 + j0 + 48] = fmaxf(s3, 0.f);
  }
  __syncthreads();
  if (tid < 128) {
    const int b = tid >> 3, jj = tid & 7;
    float s = b3[jj];
#pragma unroll 8
    for (int k = 0; k < 64; ++k) s += mlp_b[b * 65 + k] * W3[(size_t)k * 8 + jj];
    out[(size_t)(b0 + b) * 8 + jj] = s;
  }
}

extern "C" void kernel_launch(void* const* d_in, const int* in_sizes, int n_in,
                              void* d_out, int out_size, void* d_ws, size_t ws_size,
                              hipStream_t stream) {
  const float* x  = (const float*)d_in[0];
  const float* pa = (const float*)d_in[1];
  const float* Wx = (const float*)d_in[2];
  const float* Wh = (const float*)d_in[3];
  const float* bg = (const float*)d_in[4];
  const float* W1 = (const float*)d_in[5];
  const float* b1 = (const float*)d_in[6];
  const float* W2 = (const float*)d_in[7];
  const float* b2 = (const float*)d_in[8];
  const float* W3 = (const float*)d_in[9];
  const float* b3 = (const float*)d_in[10];
  (void)in_sizes; (void)n_in; (void)out_size;

  if (ws_size >= WS_NEED) {
    uint16_t* wsp = (uint16_t*)d_ws;
    pack_weights<<<dim3(536), dim3(256), 0, stream>>>(Wx, Wh, W1, wsp);
    actor_pc<<<dim3(Bsz / BB), dim3(512), 0, stream>>>(
        x, pa, bg, wsp, b1, W2, b2, W3, b3, (float*)d_out);
  } else {
    actor_fused_fb<<<dim3(Bsz / BB), dim3(256), 0, stream>>>(
        x, pa, Wx, Wh, bg, W1, b1, W2, b2, W3, b3, (float*)d_out);
  }
}